// Round 16
// baseline (157.415 us; speedup 1.0000x reference)
//
#include <hip/hip_runtime.h>

// Problem constants: b=8, c=64, hw=256, RATIO=4, HP=WP=64, N=4096.
#define NB 8
#define NC 64
#define HW 256
#define HP 64
#define NN 4096   // HP*WP

typedef unsigned short u16;
typedef unsigned int u32;
typedef __attribute__((ext_vector_type(8))) short s16x8;          // MFMA a/b frag (8 bf16)
typedef __attribute__((ext_vector_type(8))) unsigned short u16x8; // 16B bf16 vector
typedef __attribute__((ext_vector_type(4))) unsigned short u16x4; // 8B bf16 vector
typedef __attribute__((ext_vector_type(4))) float f32x4;          // MFMA acc

__device__ __forceinline__ u16 f2bf(float f) {          // fp32 -> bf16 RNE
    unsigned u = __float_as_uint(f);
    return (u16)((u + 0x7fffu + ((u >> 16) & 1u)) >> 16);
}
__device__ __forceinline__ float bf2f(u16 v) {
    return __uint_as_float(((unsigned)v) << 16);
}

// global -> LDS direct, 16B per lane. LDS dest: wave-uniform base + lane*16.
#define GLOAD16(gsrc, ldst) \
    __builtin_amdgcn_global_load_lds((const __attribute__((address_space(1))) unsigned int*)(gsrc), \
                                     (__attribute__((address_space(3))) unsigned int*)(ldst), 16, 0, 0)

// ---------------------------------------------------------------------------
// K0: fused front-end (independent, input-only; sectioned by bid):
//  bid <  512          : maxpool 4x4 + NCHW->NHWC bf16 — per-INSTRUCTION
//                        coalesced: wave reads 1 KB contiguous per load
//  512 <= bid < 1536   : W fp32 [K][N] -> WT bf16 [N][K], 128x128 tiles
//  1536 <= bid < 1936  : weight prep (Wb for convT, Bpack for conv3x3)
__global__ __launch_bounds__(256) void front_k(const float* __restrict__ x,
                                               const float* __restrict__ W,
                                               const float* __restrict__ uw,
                                               const float* __restrict__ pw,
                                               u16* __restrict__ xpc,
                                               u16* __restrict__ WTb,
                                               u16* __restrict__ Wb,
                                               u16* __restrict__ Bpack) {
    __shared__ alignas(16) char sm[32768];
    int bid = blockIdx.x;
    int t = threadIdx.x;
    if (bid < 512) {
        // ---- maxpool + NHWC: lane l = output pixel x=l; one wave load =
        //      64 lanes x float4 = 1 KB contiguous row burst ----
        u16* tile = (u16*)sm;                   // [64][66]
        int b = bid >> 6, y = bid & 63;
        int w = t >> 6, l = t & 63;
#pragma unroll
        for (int cc = 0; cc < 16; ++cc) {
            int c = w * 16 + cc;
            const float* p = x + ((long)(b * 64 + c) * 256 + y * 4) * 256 + l * 4;
            float m = -3.4e38f;
#pragma unroll
            for (int r = 0; r < 4; ++r) {
                float4 v = *(const float4*)(p + r * 256);
                m = fmaxf(m, fmaxf(fmaxf(v.x, v.y), fmaxf(v.z, v.w)));
            }
            tile[c * 66 + l] = f2bf(m);
        }
        __syncthreads();
        int xo = t >> 2, cp = t & 3;
        u16x8 o0, o1;
#pragma unroll
        for (int e = 0; e < 8; ++e) o0[e] = tile[(cp * 16 + e) * 66 + xo];
#pragma unroll
        for (int e = 0; e < 8; ++e) o1[e] = tile[(cp * 16 + 8 + e) * 66 + xo];
        u16* dst = xpc + ((long)(b * 4096 + y * 64 + xo)) * 64 + cp * 16;
        *(u16x8*)dst = o0;
        *(u16x8*)(dst + 8) = o1;
    } else if (bid < 1536) {
        // ---- W transpose, 128x128 tiles (512B reads, 256B writes) ----
        u16* tile = (u16*)sm;                    // [128][128] bf16, swizzled
        int tb = bid - 512;
        int k0 = (tb >> 5) * 128;
        int n0 = (tb & 31) * 128;
        int nq = t & 31;
#pragma unroll
        for (int p = 0; p < 4; ++p) {
            int kq = (t >> 5) + p * 8;
            float4 v[4];
#pragma unroll
            for (int j = 0; j < 4; ++j)
                v[j] = *(const float4*)&W[(long)(k0 + kq * 4 + j) * 4096 + n0 + nq * 4];
#pragma unroll
            for (int jn = 0; jn < 4; ++jn) {
                int n = nq * 4 + jn;
                u16x4 c4;
                c4[0] = f2bf(((const float*)&v[0])[jn]);
                c4[1] = f2bf(((const float*)&v[1])[jn]);
                c4[2] = f2bf(((const float*)&v[2])[jn]);
                c4[3] = f2bf(((const float*)&v[3])[jn]);
                *(u16x4*)((char*)tile + n * 256 + ((kq * 8) ^ ((n & 15) << 4))) = c4;
            }
        }
        __syncthreads();
#pragma unroll
        for (int q = 0; q < 8; ++q) {
            int chunk = t + q * 256;
            int n = chunk >> 4, seg = chunk & 15;
            u16x8 o = *(const u16x8*)((const char*)tile + n * 256 +
                                      ((seg * 16) ^ ((n & 15) << 4)));
            *(u16x8*)&WTb[(long)(n0 + n) * 4096 + k0 + seg * 8] = o;
        }
    } else {
        // ---- small weight prep ----
        int pbid = bid - 1536;
        if (pbid < 256) {
            int idx = pbid * 256 + t;
            int c = idx & 63;
            int n = idx >> 6;
            int o = n >> 4, i = (n >> 2) & 3, j = n & 3;
            Wb[idx] = f2bf(uw[((c * 64 + o) * 4 + i) * 4 + j]);
        } else {
            int idx = (pbid - 256) * 256 + t;
            if (idx >= 36864) return;
            int e = idx & 7, l = (idx >> 3) & 63, nf = (idx >> 9) & 3, s = idx >> 11;
            int ch = s & 1, kd = s >> 1;
            int dy = kd / 3, dx = kd % 3;
            int o  = nf * 16 + (l & 15);
            int ci = ch * 32 + (l >> 4) * 8 + e;
            Bpack[idx] = f2bf(pw[((o * 64 + ci) * 3 + dy) * 3 + dx]);
        }
    }
}

// ---------------------------------------------------------------------------
// K2: conv3x3 implicit-GEMM MFMA + FUSED Gram accumulation (R11-verified).
__global__ __launch_bounds__(256) void convgram_k(const u16* __restrict__ xpc,
                                                  const u16* __restrict__ Bpack,
                                                  const float* __restrict__ pb,
                                                  float* __restrict__ G) {
    __shared__ alignas(16) u16 ldsIn[3 * 66 * 64];   // 25344 B
    __shared__ alignas(16) u16 ldsX[64 * 64];        // 8 KB X-tile, swizzled rows
    int bid = blockIdx.x;
    int b = bid >> 6, y = bid & 63;
    int t = threadIdx.x;
    int w = t >> 6, l = t & 63;
    int lr = l & 15, ksub = l >> 4;

    if (t < 48) {
        int r = t >> 4, q = t & 15;
        int off = r * 8448 + (q < 8 ? q * 16 : 8320 + (q - 8) * 16);
        *(u16x8*)((char*)ldsIn + off) = (u16x8){0, 0, 0, 0, 0, 0, 0, 0};
    }
#pragma unroll
    for (int i = 0; i < 6; ++i) {
        int r  = i >> 1;
        int ya = y - 1 + r;
        int wro = (i & 1) * 4096 + t * 16;
        int dst = r * 8448 + 128 + wro;
        if (ya >= 0 && ya < 64) {
            int xsl = 1 + (wro >> 7);
            int srcoff = (wro & ~127) | ((wro & 127) ^ ((xsl & 7) << 4));
            GLOAD16((const char*)xpc + (long)(b * 64 + ya) * 8192 + srcoff,
                    (char*)ldsIn + dst);
        } else {
            *(u16x8*)((char*)ldsIn + dst) = (u16x8){0, 0, 0, 0, 0, 0, 0, 0};
        }
    }
    __syncthreads();

    f32x4 acc[4];
#pragma unroll
    for (int mf = 0; mf < 4; ++mf) acc[mf] = (f32x4){0.f, 0.f, 0.f, 0.f};

#pragma unroll
    for (int kd = 0; kd < 9; ++kd) {
        int dy = kd / 3, dx = kd % 3;
#pragma unroll
        for (int ch = 0; ch < 2; ++ch) {
            int s = kd * 2 + ch;
            s16x8 bfrag = *(const s16x8*)(Bpack + ((s * 4 + w) * 64 + l) * 8);
#pragma unroll
            for (int mf = 0; mf < 4; ++mf) {
                int xsl  = mf * 16 + lr + dx;
                int coff = (ch * 64 + ksub * 16) ^ ((xsl & 7) << 4);
                s16x8 af = *(const s16x8*)((const char*)ldsIn +
                                           dy * 8448 + xsl * 128 + coff);
                acc[mf] = __builtin_amdgcn_mfma_f32_16x16x32_bf16(
                    af, bfrag, acc[mf], 0, 0, 0);
            }
        }
    }
    int o = w * 16 + lr;
    float bias = pb[o];
#pragma unroll
    for (int mf = 0; mf < 4; ++mf)
#pragma unroll
        for (int rp = 0; rp < 2; ++rp) {
            u16 lo = f2bf(fmaxf(acc[mf][rp * 2]     + bias, 0.f));
            u16 hi = f2bf(fmaxf(acc[mf][rp * 2 + 1] + bias, 0.f));
            int nb   = (mf * 16 + ksub * 4 + rp * 2) * 2;
            int boff = nb ^ ((o & 7) << 4);
            *(u32*)((char*)ldsX + o * 128 + boff) = (u32)lo | ((u32)hi << 16);
        }
    __syncthreads();

    f32x4 g[4];
#pragma unroll
    for (int nf = 0; nf < 4; ++nf) g[nf] = (f32x4){0.f, 0.f, 0.f, 0.f};
#pragma unroll
    for (int kk = 0; kk < 2; ++kk) {
        int kb = kk * 64 + ksub * 16;
        int arow = w * 16 + lr;
        s16x8 af = *(const s16x8*)((const char*)ldsX + arow * 128 +
                                   (kb ^ ((arow & 7) << 4)));
#pragma unroll
        for (int nf = 0; nf < 4; ++nf) {
            int brow = nf * 16 + lr;
            s16x8 bf = *(const s16x8*)((const char*)ldsX + brow * 128 +
                                       (kb ^ ((brow & 7) << 4)));
            g[nf] = __builtin_amdgcn_mfma_f32_16x16x32_bf16(af, bf, g[nf], 0, 0, 0);
        }
    }
    float* Gb = G + b * 4096;
#pragma unroll
    for (int nf = 0; nf < 4; ++nf)
#pragma unroll
        for (int r = 0; r < 4; ++r)
            atomicAdd(&Gb[(w * 16 + ksub * 4 + r) * 64 + nf * 16 + lr], g[nf][r]);
}

// ---------------------------------------------------------------------------
// K5: diffuse via MFMA with fused L-build (R8-verified).
__global__ __launch_bounds__(256) void diffuse_mfma_k(const float* __restrict__ G,
                                                      const u16* __restrict__ xpc,
                                                      u16* __restrict__ Ab16) {
    __shared__ alignas(16) u16 lds[128 * 64];
    __shared__ alignas(16) u16 ldsL[64 * 64];
    __shared__ float nrm[64], dvv[64];
    int n0 = blockIdx.x * 128;
    int b  = blockIdx.y;
    int t = threadIdx.x;
    int w = t >> 6, l = t & 63;
    int lr = l & 15, ksub = l >> 4;

#pragma unroll
    for (int i = 0; i < 4; ++i) {
        int d = i * 4096 + t * 16;
        int row = d >> 7, off = d & 127;
        GLOAD16((const char*)xpc + ((long)(b * 4096 + n0 + row)) * 128 +
                (off ^ ((row & 7) << 4)),
                (char*)lds + d);
    }

    const float* Gb = G + b * 4096;
    if (t < 64) nrm[t] = fmaxf(sqrtf(Gb[t * 64 + t]), 1e-12f);
    __syncthreads();
    if (t < 64) {
        float nc = nrm[t];
        float rs = 0.f;
        for (int d = 0; d < 64; ++d) rs += Gb[t * 64 + d] / (nc * nrm[d]);
        float dd = 1.0f / sqrtf(rs + 1e-8f);
        if (!(dd <= 3.0e38f)) dd = 0.0f;
        dvv[t] = dd;
    }
    __syncthreads();
    {
        int c = t >> 2;
        int dbase = (t & 3) * 16;
        float nc = nrm[c], dc = dvv[c];
#pragma unroll
        for (int dp2 = 0; dp2 < 8; ++dp2) {
            int d0 = dbase + dp2 * 2;
            float A0 = Gb[c * 64 + d0]     / (nc * nrm[d0]);
            float A1 = Gb[c * 64 + d0 + 1] / (nc * nrm[d0 + 1]);
            float v0 = ((c == d0)     ? 1.f : 0.f) - dc * A0 * dvv[d0];
            float v1 = ((c == d0 + 1) ? 1.f : 0.f) - dc * A1 * dvv[d0 + 1];
            int o = c * 64 + (d0 ^ ((c & 7) << 3));
            *(u32*)&ldsL[o] = (u32)f2bf(v0) | ((u32)f2bf(v1) << 16);
        }
    }
    __syncthreads();

    f32x4 acc[4][2];
#pragma unroll
    for (int mf = 0; mf < 4; ++mf)
#pragma unroll
        for (int nq = 0; nq < 2; ++nq) acc[mf][nq] = (f32x4){0.f, 0.f, 0.f, 0.f};

#pragma unroll
    for (int kk = 0; kk < 2; ++kk) {
        s16x8 bfr[2];
#pragma unroll
        for (int nq = 0; nq < 2; ++nq) {
            int brow = w * 32 + nq * 16 + lr;
            bfr[nq] = *(const s16x8*)((const char*)lds + brow * 128 +
                                      ((kk * 64 + ksub * 16) ^ ((brow & 7) << 4)));
        }
#pragma unroll
        for (int mf = 0; mf < 4; ++mf) {
            int arow = mf * 16 + lr;
            s16x8 af = *(const s16x8*)((const char*)ldsL + arow * 128 +
                                       ((kk * 64 + ksub * 16) ^ ((arow & 7) << 4)));
#pragma unroll
            for (int nq = 0; nq < 2; ++nq)
                acc[mf][nq] = __builtin_amdgcn_mfma_f32_16x16x32_bf16(
                    af, bfr[nq], acc[mf][nq], 0, 0, 0);
        }
    }
#pragma unroll
    for (int mf = 0; mf < 4; ++mf)
#pragma unroll
        for (int nq = 0; nq < 2; ++nq)
#pragma unroll
            for (int r = 0; r < 4; ++r)
                Ab16[((long)(b * 64 + mf * 16 + (l >> 4) * 4 + r)) * 4096 +
                     n0 + w * 32 + nq * 16 + lr] = f2bf(acc[mf][nq][r]);
}

// ---------------------------------------------------------------------------
// K6: bf16 MFMA GEMM, m97-style single-buffer 128x128 tile, KSPLIT=4,
// fragment-native dump (R11/R12-verified fastest gemm config).
#define KSPLIT 4
#define KSLICE 1024
__global__ __launch_bounds__(256) void gemm_mfma_k(const u16* __restrict__ A,
                                                   const u16* __restrict__ WT,
                                                   u16* __restrict__ Cp) {
    __shared__ alignas(16) u16 ldsA[8192];   // 16 KB
    __shared__ alignas(16) u16 ldsB[8192];   // 16 KB
    int bid = blockIdx.x;                    // 512 blocks
    int swz = (bid & 7) * 64 + (bid >> 3);   // XCD-chunked (512 % 8 == 0)
    int m0 = (swz & 3) * 128;
    int n0 = ((swz >> 2) & 31) * 128;
    int z  = swz >> 7;
    int t = threadIdx.x;
    int w = t >> 6, l = t & 63;
    int wr = w >> 1, wc = w & 1;
    int lr = l & 15;
    int lk = (l >> 4) << 4;

    f32x4 acc[4][4];
#pragma unroll
    for (int mf = 0; mf < 4; ++mf)
#pragma unroll
        for (int nf = 0; nf < 4; ++nf) acc[mf][nf] = (f32x4){0.f, 0.f, 0.f, 0.f};

    const char* Ab = (const char*)(A  + (long)m0 * 4096 + z * KSLICE);
    const char* Bb = (const char*)(WT + (long)n0 * 4096 + z * KSLICE);

    for (int k0 = 0; k0 < KSLICE; k0 += 64) {
        __syncthreads();
#pragma unroll
        for (int i = 0; i < 4; ++i) {
            int d   = i * 4096 + t * 16;
            int row = d >> 7;
            int off = d & 127;
            int sk  = off ^ ((row & 7) << 4);
            GLOAD16(Ab + (long)row * 8192 + k0 * 2 + sk, (char*)ldsA + d);
            GLOAD16(Bb + (long)row * 8192 + k0 * 2 + sk, (char*)ldsB + d);
        }
        __syncthreads();
#pragma unroll
        for (int kk = 0; kk < 2; ++kk) {
            s16x8 af[4], bf[4];
#pragma unroll
            for (int f = 0; f < 4; ++f) {
                int ar = wr * 64 + f * 16 + lr;
                af[f] = *(const s16x8*)((const char*)ldsA + ar * 128 +
                                        ((kk * 64 + lk) ^ ((ar & 7) << 4)));
                int br = wc * 64 + f * 16 + lr;
                bf[f] = *(const s16x8*)((const char*)ldsB + br * 128 +
                                        ((kk * 64 + lk) ^ ((br & 7) << 4)));
            }
#pragma unroll
            for (int mf = 0; mf < 4; ++mf)
#pragma unroll
                for (int nf = 0; nf < 4; ++nf)
                    acc[mf][nf] = __builtin_amdgcn_mfma_f32_16x16x32_bf16(
                        af[mf], bf[nf], acc[mf][nf], 0, 0, 0);
        }
    }
    // fragment-native dump: 8 coalesced 16B stores, zero scatter
    int tile = (swz & 3) * 32 + ((swz >> 2) & 31);
    u16 carr[64];
#pragma unroll
    for (int mf = 0; mf < 4; ++mf)
#pragma unroll
        for (int nf = 0; nf < 4; ++nf)
#pragma unroll
            for (int r = 0; r < 4; ++r)
                carr[mf * 16 + nf * 4 + r] = f2bf(acc[mf][nf][r]);
    u16* dp = Cp + ((long)(z * 128 + tile) * 256 + t) * 64;
#pragma unroll
    for (int v8 = 0; v8 < 8; ++v8)
        *(u16x8*)&dp[v8 * 8] = *(const u16x8*)&carr[v8 * 8];
}

// ---------------------------------------------------------------------------
// K6b: reduce 4 z-dumps + transpose -> A2[b*4096+n][c] bf16 (R10-verified).
__global__ __launch_bounds__(256) void reduce4T_k(const u16* __restrict__ Cp,
                                                  u16* __restrict__ A2) {
    __shared__ u16 ldsT[128 * 128];              // [pix][mrow swizzled], 32 KB
    int tile = blockIdx.x;                       // 0..127
    int tm = tile >> 5, tn = tile & 31;
    int n0 = tn * 128;
    int t = threadIdx.x;
    int w = t >> 6, l = t & 63;
    int wr = w >> 1, wc = w & 1, lr = l & 15;

    float s[64];
#pragma unroll
    for (int k = 0; k < 64; ++k) s[k] = 0.f;

    const u16* dp = Cp + ((long)tile * 256 + t) * 64;
#pragma unroll
    for (int z = 0; z < KSPLIT; ++z) {
        const u16* pz = dp + (long)z * 2097152;  // 128*256*64
#pragma unroll
        for (int v8 = 0; v8 < 8; ++v8) {
            u16x8 vv = *(const u16x8*)&pz[v8 * 8];
#pragma unroll
            for (int e = 0; e < 8; ++e) s[v8 * 8 + e] += bf2f(vv[e]);
        }
    }
    // scatter to LDS transposed: ldsT[pix][mrow ^ swz]
#pragma unroll
    for (int mf = 0; mf < 4; ++mf)
#pragma unroll
        for (int nf = 0; nf < 4; ++nf) {
            int mbase = wr * 64 + mf * 16 + (l >> 4) * 4;    // 4-aligned
            int pix   = wc * 64 + nf * 16 + lr;
            int g = (mbase >> 3) ^ (pix & 7);
            int o = pix * 128 + g * 8 + (mbase & 7);
            u32 w0 = (u32)f2bf(s[mf * 16 + nf * 4 + 0]) |
                     ((u32)f2bf(s[mf * 16 + nf * 4 + 1]) << 16);
            u32 w1 = (u32)f2bf(s[mf * 16 + nf * 4 + 2]) |
                     ((u32)f2bf(s[mf * 16 + nf * 4 + 3]) << 16);
            *(u32*)&ldsT[o]     = w0;
            *(u32*)&ldsT[o + 2] = w1;
        }
    __syncthreads();
    int pix_l = t >> 1, bh = t & 1;
    u16* dst = A2 + ((long)((2 * tm + bh) * 4096 + n0 + pix_l)) * 64;
#pragma unroll
    for (int gg = 0; gg < 8; ++gg) {
        int q = bh * 8 + gg;
        u16x8 vv = *(const u16x8*)&ldsT[pix_l * 128 + (q ^ (pix_l & 7)) * 8];
        *(u16x8*)&dst[gg * 8] = vv;
    }
}

// ---------------------------------------------------------------------------
// K7: convT as MFMA GEMM reading clean A2 (R14-verified lean form), 1-D XCD
// grid: the 8 nt-sharers of an A2-tile co-reside on one XCD (L2-hot re-reads).
__global__ __launch_bounds__(256) void convT_mfma_k(const u16* __restrict__ A2,
                                                    const u16* __restrict__ Wb,
                                                    const float* __restrict__ ub,
                                                    const float* __restrict__ x,
                                                    float* __restrict__ out) {
    __shared__ alignas(16) char smem[34816];     // staging 32KB | C-bounce 128x68 f32
    u16*   ldsA = (u16*)smem;
    u16*   ldsB = (u16*)(smem + 16384);
    float* ldsC = (float*)smem;
    int bid = blockIdx.x;                        // 0..2047
    int swzb = (bid & 7) * 256 + (bid >> 3);     // XCD-chunked (2048 % 8 == 0)
    int mt = swzb >> 3;                          // 0..255
    int nt = swzb & 7;                           // 0..7
    int m0 = mt * 128;
    int n0 = nt * 128;
    int t = threadIdx.x;
    int w = t >> 6, l = t & 63;
    int wr = w >> 1, wc = w & 1;
    int lr = l & 15;
    int lkb = (l >> 4) << 4;

    const char* Ab = (const char*)(A2 + (long)m0 * 64);
    const char* Bb = (const char*)(Wb + (long)n0 * 64);
#pragma unroll
    for (int i = 0; i < 4; ++i) {
        int d = i * 4096 + t * 16;
        int srcoff = (d & ~127) | ((d & 127) ^ (((d >> 7) & 7) << 4));
        GLOAD16(Ab + srcoff, (char*)ldsA + d);
        GLOAD16(Bb + srcoff, (char*)ldsB + d);
    }
    __syncthreads();

    f32x4 acc[4][4];
#pragma unroll
    for (int mf = 0; mf < 4; ++mf)
#pragma unroll
        for (int nf = 0; nf < 4; ++nf) acc[mf][nf] = (f32x4){0.f, 0.f, 0.f, 0.f};

#pragma unroll
    for (int kk = 0; kk < 2; ++kk) {
        s16x8 af[4], bfg[4];
#pragma unroll
        for (int f = 0; f < 4; ++f) {
            int ar = wr * 64 + f * 16 + lr;
            af[f] = *(const s16x8*)((const char*)ldsA + ar * 128 +
                                    ((kk * 64 + lkb) ^ ((ar & 7) << 4)));
            int br = wc * 64 + f * 16 + lr;
            bfg[f] = *(const s16x8*)((const char*)ldsB + br * 128 +
                                     ((kk * 64 + lkb) ^ ((br & 7) << 4)));
        }
#pragma unroll
        for (int mf = 0; mf < 4; ++mf)
#pragma unroll
            for (int nf = 0; nf < 4; ++nf)
                acc[mf][nf] = __builtin_amdgcn_mfma_f32_16x16x32_bf16(
                    af[mf], bfg[nf], acc[mf][nf], 0, 0, 0);
    }
    __syncthreads();                             // ldsA/B dead; reuse as ldsC

#pragma unroll
    for (int nh = 0; nh < 2; ++nh) {
        if (nh) __syncthreads();
        if (wc == nh) {
#pragma unroll
            for (int mf = 0; mf < 4; ++mf)
#pragma unroll
                for (int nf = 0; nf < 4; ++nf)
#pragma unroll
                    for (int r = 0; r < 4; ++r) {
                        int row = wr * 64 + mf * 16 + (l >> 4) * 4 + r;
                        int col = nf * 16 + lr;
                        ldsC[row * 68 + (col ^ (((row >> 3) & 7) << 2))] =
                            acc[mf][nf][r];
                    }
        }
        __syncthreads();
#pragma unroll
        for (int q = 0; q < 2; ++q) {
            int idx = q * 256 + t;
            int ml = idx & 127;
            int oo = idx >> 7;
            int o  = nt * 8 + nh * 4 + oo;
            float bias = ub[o];
            int mg = m0 + ml;
            int b = mg >> 12, pix = mg & 4095;
            int h2 = pix >> 6, ww = pix & 63;
            long base = ((long)(b * 64 + o) * 256 + h2 * 4) * 256 + ww * 4;
#pragma unroll
            for (int i = 0; i < 4; ++i) {
                f32x4 cv = *(const f32x4*)&ldsC[ml * 68 +
                            ((oo * 16 + i * 4) ^ (((ml >> 3) & 7) << 2))];
                float4 xi = *(const float4*)&x[base + i * 256];
                float4 rr;
                rr.x = fmaxf(cv[0] + bias + xi.x, 0.f);
                rr.y = fmaxf(cv[1] + bias + xi.y, 0.f);
                rr.z = fmaxf(cv[2] + bias + xi.z, 0.f);
                rr.w = fmaxf(cv[3] + bias + xi.w, 0.f);
                *(float4*)&out[base + i * 256] = rr;
            }
        }
    }
}

// ---------------------------------------------------------------------------
extern "C" void kernel_launch(void* const* d_in, const int* in_sizes, int n_in,
                              void* d_out, int out_size, void* d_ws, size_t ws_size,
                              hipStream_t stream) {
    const float* x      = (const float*)d_in[0];
    const float* weight = (const float*)d_in[1];
    const float* pih_w  = (const float*)d_in[2];
    const float* pih_b  = (const float*)d_in[3];
    const float* up_w   = (const float*)d_in[4];
    const float* up_b   = (const float*)d_in[5];
    float* out = (float*)d_out;
    float* ws  = (float*)d_ws;

    // workspace layout (float offsets)
    u16*   xpc   = (u16*)ws;                   // 2,097,152 u16 NHWC bf16 pooled
    u16*   Ab16  = (u16*)(ws + 3145728);       // 2,097,152 u16 GEMM A bf16
    float* G     = ws + 4194304;               // 32,768 f
    u16*   Wb    = (u16*)(ws + 4259840);       // 65,536 u16 convT B^T bf16
    u16*   WTb   = (u16*)(ws + 4325376);       // 16,777,216 u16 WT bf16 [N][K]
    u16*   Cp    = (u16*)(ws + 12713984);      // 8,388,608 u16: 4 z-partial dumps
    u16*   Bpack = Cp + 2097152;               // conv weights (dead until gemm)
    u16*   A2    = (u16*)ws;                   // out2^T bf16 (xpc dead after diffuse)

    hipMemsetAsync(G, 0, 32768 * sizeof(float), stream);
    front_k       <<<1936, 256, 0, stream>>>(x, weight, up_w, pih_w,
                                             xpc, WTb, Wb, Bpack);
    convgram_k    <<<512, 256, 0, stream>>>(xpc, Bpack, pih_b, G);
    diffuse_mfma_k<<<dim3(32, 8), 256, 0, stream>>>(G, xpc, Ab16);
    gemm_mfma_k   <<<512, 256, 0, stream>>>(Ab16, WTb, Cp);
    reduce4T_k    <<<128, 256, 0, stream>>>(Cp, A2);
    convT_mfma_k  <<<2048, 256, 0, stream>>>(A2, Wb, up_b, x, out);
}

// Round 17
// 153.739 us; speedup vs baseline: 1.0239x; 1.0239x over previous
//
#include <hip/hip_runtime.h>

// Problem constants: b=8, c=64, hw=256, RATIO=4, HP=WP=64, N=4096.
#define NB 8
#define NC 64
#define HW 256
#define HP 64
#define NN 4096   // HP*WP

typedef unsigned short u16;
typedef unsigned int u32;
typedef __attribute__((ext_vector_type(8))) short s16x8;          // MFMA a/b frag (8 bf16)
typedef __attribute__((ext_vector_type(8))) unsigned short u16x8; // 16B bf16 vector
typedef __attribute__((ext_vector_type(4))) unsigned short u16x4; // 8B bf16 vector
typedef __attribute__((ext_vector_type(4))) float f32x4;          // MFMA acc

__device__ __forceinline__ u16 f2bf(float f) {          // fp32 -> bf16 RNE
    unsigned u = __float_as_uint(f);
    return (u16)((u + 0x7fffu + ((u >> 16) & 1u)) >> 16);
}
__device__ __forceinline__ float bf2f(u16 v) {
    return __uint_as_float(((unsigned)v) << 16);
}

// global -> LDS direct, 16B per lane. LDS dest: wave-uniform base + lane*16.
#define GLOAD16(gsrc, ldst) \
    __builtin_amdgcn_global_load_lds((const __attribute__((address_space(1))) unsigned int*)(gsrc), \
                                     (__attribute__((address_space(3))) unsigned int*)(ldst), 16, 0, 0)

// ---------------------------------------------------------------------------
// K0: fused front-end (independent, input-only; sectioned by bid):
//  bid <  512          : maxpool 4x4 + NCHW->NHWC bf16 — ILP-batched loads
//  512 <= bid < 1536   : W fp32 [K][N] -> WT bf16 [N][K] — ILP-batched loads
//  1536 <= bid < 1936  : weight prep (Wb for convT, Bpack for conv3x3)
__global__ __launch_bounds__(256) void front_k(const float* __restrict__ x,
                                               const float* __restrict__ W,
                                               const float* __restrict__ uw,
                                               const float* __restrict__ pw,
                                               u16* __restrict__ xpc,
                                               u16* __restrict__ WTb,
                                               u16* __restrict__ Wb,
                                               u16* __restrict__ Bpack) {
    __shared__ alignas(16) char sm[32768];
    int bid = blockIdx.x;
    int t = threadIdx.x;
    if (bid < 512) {
        // ---- maxpool + NHWC: lane l = pixel x; wave w = channels w*16..+15.
        //      All 16 channel-loads of a row issued before any fmax (ILP=16).
        u16* tile = (u16*)sm;                   // [64][66]
        int b = bid >> 6, y = bid & 63;
        int w = t >> 6, l = t & 63;
        const float* base = x + ((long)(b * 64 + w * 16) * 256 + y * 4) * 256 + l * 4;
        float4 v[16];
        float m[16];
#pragma unroll
        for (int r = 0; r < 4; ++r) {
#pragma unroll
            for (int cc = 0; cc < 16; ++cc)
                v[cc] = *(const float4*)(base + (long)cc * 65536 + r * 256);
#pragma unroll
            for (int cc = 0; cc < 16; ++cc) {
                float h = fmaxf(fmaxf(v[cc].x, v[cc].y), fmaxf(v[cc].z, v[cc].w));
                m[cc] = (r == 0) ? h : fmaxf(m[cc], h);
            }
        }
#pragma unroll
        for (int cc = 0; cc < 16; ++cc)
            tile[(w * 16 + cc) * 66 + l] = f2bf(m[cc]);
        __syncthreads();
        int xo = t >> 2, cp = t & 3;
        u16x8 o0, o1;
#pragma unroll
        for (int e = 0; e < 8; ++e) o0[e] = tile[(cp * 16 + e) * 66 + xo];
#pragma unroll
        for (int e = 0; e < 8; ++e) o1[e] = tile[(cp * 16 + 8 + e) * 66 + xo];
        u16* dst = xpc + ((long)(b * 4096 + y * 64 + xo)) * 64 + cp * 16;
        *(u16x8*)dst = o0;
        *(u16x8*)(dst + 8) = o1;
    } else if (bid < 1536) {
        // ---- W transpose, 128x128 tiles; all 16 loads issued up front ----
        u16* tile = (u16*)sm;                    // [128][128] bf16, swizzled
        int tb = bid - 512;
        int k0 = (tb >> 5) * 128;
        int n0 = (tb & 31) * 128;
        int nq = t & 31;
        float4 v[16];
#pragma unroll
        for (int p = 0; p < 4; ++p) {
            int kq = (t >> 5) + p * 8;
#pragma unroll
            for (int j = 0; j < 4; ++j)
                v[p * 4 + j] = *(const float4*)&W[(long)(k0 + kq * 4 + j) * 4096 +
                                                  n0 + nq * 4];
        }
#pragma unroll
        for (int p = 0; p < 4; ++p) {
            int kq = (t >> 5) + p * 8;
#pragma unroll
            for (int jn = 0; jn < 4; ++jn) {
                int n = nq * 4 + jn;
                u16x4 c4;
                c4[0] = f2bf(((const float*)&v[p * 4 + 0])[jn]);
                c4[1] = f2bf(((const float*)&v[p * 4 + 1])[jn]);
                c4[2] = f2bf(((const float*)&v[p * 4 + 2])[jn]);
                c4[3] = f2bf(((const float*)&v[p * 4 + 3])[jn]);
                *(u16x4*)((char*)tile + n * 256 + ((kq * 8) ^ ((n & 15) << 4))) = c4;
            }
        }
        __syncthreads();
#pragma unroll
        for (int q = 0; q < 8; ++q) {
            int chunk = t + q * 256;
            int n = chunk >> 4, seg = chunk & 15;
            u16x8 o = *(const u16x8*)((const char*)tile + n * 256 +
                                      ((seg * 16) ^ ((n & 15) << 4)));
            *(u16x8*)&WTb[(long)(n0 + n) * 4096 + k0 + seg * 8] = o;
        }
    } else {
        // ---- small weight prep ----
        int pbid = bid - 1536;
        if (pbid < 256) {
            int idx = pbid * 256 + t;
            int c = idx & 63;
            int n = idx >> 6;
            int o = n >> 4, i = (n >> 2) & 3, j = n & 3;
            Wb[idx] = f2bf(uw[((c * 64 + o) * 4 + i) * 4 + j]);
        } else {
            int idx = (pbid - 256) * 256 + t;
            if (idx >= 36864) return;
            int e = idx & 7, l = (idx >> 3) & 63, nf = (idx >> 9) & 3, s = idx >> 11;
            int ch = s & 1, kd = s >> 1;
            int dy = kd / 3, dx = kd % 3;
            int o  = nf * 16 + (l & 15);
            int ci = ch * 32 + (l >> 4) * 8 + e;
            Bpack[idx] = f2bf(pw[((o * 64 + ci) * 3 + dy) * 3 + dx]);
        }
    }
}

// ---------------------------------------------------------------------------
// K2: conv3x3 implicit-GEMM MFMA + FUSED Gram accumulation (R11-verified).
__global__ __launch_bounds__(256) void convgram_k(const u16* __restrict__ xpc,
                                                  const u16* __restrict__ Bpack,
                                                  const float* __restrict__ pb,
                                                  float* __restrict__ G) {
    __shared__ alignas(16) u16 ldsIn[3 * 66 * 64];   // 25344 B
    __shared__ alignas(16) u16 ldsX[64 * 64];        // 8 KB X-tile, swizzled rows
    int bid = blockIdx.x;
    int b = bid >> 6, y = bid & 63;
    int t = threadIdx.x;
    int w = t >> 6, l = t & 63;
    int lr = l & 15, ksub = l >> 4;

    if (t < 48) {
        int r = t >> 4, q = t & 15;
        int off = r * 8448 + (q < 8 ? q * 16 : 8320 + (q - 8) * 16);
        *(u16x8*)((char*)ldsIn + off) = (u16x8){0, 0, 0, 0, 0, 0, 0, 0};
    }
#pragma unroll
    for (int i = 0; i < 6; ++i) {
        int r  = i >> 1;
        int ya = y - 1 + r;
        int wro = (i & 1) * 4096 + t * 16;
        int dst = r * 8448 + 128 + wro;
        if (ya >= 0 && ya < 64) {
            int xsl = 1 + (wro >> 7);
            int srcoff = (wro & ~127) | ((wro & 127) ^ ((xsl & 7) << 4));
            GLOAD16((const char*)xpc + (long)(b * 64 + ya) * 8192 + srcoff,
                    (char*)ldsIn + dst);
        } else {
            *(u16x8*)((char*)ldsIn + dst) = (u16x8){0, 0, 0, 0, 0, 0, 0, 0};
        }
    }
    __syncthreads();

    f32x4 acc[4];
#pragma unroll
    for (int mf = 0; mf < 4; ++mf) acc[mf] = (f32x4){0.f, 0.f, 0.f, 0.f};

#pragma unroll
    for (int kd = 0; kd < 9; ++kd) {
        int dy = kd / 3, dx = kd % 3;
#pragma unroll
        for (int ch = 0; ch < 2; ++ch) {
            int s = kd * 2 + ch;
            s16x8 bfrag = *(const s16x8*)(Bpack + ((s * 4 + w) * 64 + l) * 8);
#pragma unroll
            for (int mf = 0; mf < 4; ++mf) {
                int xsl  = mf * 16 + lr + dx;
                int coff = (ch * 64 + ksub * 16) ^ ((xsl & 7) << 4);
                s16x8 af = *(const s16x8*)((const char*)ldsIn +
                                           dy * 8448 + xsl * 128 + coff);
                acc[mf] = __builtin_amdgcn_mfma_f32_16x16x32_bf16(
                    af, bfrag, acc[mf], 0, 0, 0);
            }
        }
    }
    int o = w * 16 + lr;
    float bias = pb[o];
#pragma unroll
    for (int mf = 0; mf < 4; ++mf)
#pragma unroll
        for (int rp = 0; rp < 2; ++rp) {
            u16 lo = f2bf(fmaxf(acc[mf][rp * 2]     + bias, 0.f));
            u16 hi = f2bf(fmaxf(acc[mf][rp * 2 + 1] + bias, 0.f));
            int nb   = (mf * 16 + ksub * 4 + rp * 2) * 2;
            int boff = nb ^ ((o & 7) << 4);
            *(u32*)((char*)ldsX + o * 128 + boff) = (u32)lo | ((u32)hi << 16);
        }
    __syncthreads();

    f32x4 g[4];
#pragma unroll
    for (int nf = 0; nf < 4; ++nf) g[nf] = (f32x4){0.f, 0.f, 0.f, 0.f};
#pragma unroll
    for (int kk = 0; kk < 2; ++kk) {
        int kb = kk * 64 + ksub * 16;
        int arow = w * 16 + lr;
        s16x8 af = *(const s16x8*)((const char*)ldsX + arow * 128 +
                                   (kb ^ ((arow & 7) << 4)));
#pragma unroll
        for (int nf = 0; nf < 4; ++nf) {
            int brow = nf * 16 + lr;
            s16x8 bf = *(const s16x8*)((const char*)ldsX + brow * 128 +
                                       (kb ^ ((brow & 7) << 4)));
            g[nf] = __builtin_amdgcn_mfma_f32_16x16x32_bf16(af, bf, g[nf], 0, 0, 0);
        }
    }
    float* Gb = G + b * 4096;
#pragma unroll
    for (int nf = 0; nf < 4; ++nf)
#pragma unroll
        for (int r = 0; r < 4; ++r)
            atomicAdd(&Gb[(w * 16 + ksub * 4 + r) * 64 + nf * 16 + lr], g[nf][r]);
}

// ---------------------------------------------------------------------------
// K5: diffuse via MFMA with fused L-build (R8-verified).
__global__ __launch_bounds__(256) void diffuse_mfma_k(const float* __restrict__ G,
                                                      const u16* __restrict__ xpc,
                                                      u16* __restrict__ Ab16) {
    __shared__ alignas(16) u16 lds[128 * 64];
    __shared__ alignas(16) u16 ldsL[64 * 64];
    __shared__ float nrm[64], dvv[64];
    int n0 = blockIdx.x * 128;
    int b  = blockIdx.y;
    int t = threadIdx.x;
    int w = t >> 6, l = t & 63;
    int lr = l & 15, ksub = l >> 4;

#pragma unroll
    for (int i = 0; i < 4; ++i) {
        int d = i * 4096 + t * 16;
        int row = d >> 7, off = d & 127;
        GLOAD16((const char*)xpc + ((long)(b * 4096 + n0 + row)) * 128 +
                (off ^ ((row & 7) << 4)),
                (char*)lds + d);
    }

    const float* Gb = G + b * 4096;
    if (t < 64) nrm[t] = fmaxf(sqrtf(Gb[t * 64 + t]), 1e-12f);
    __syncthreads();
    if (t < 64) {
        float nc = nrm[t];
        float rs = 0.f;
        for (int d = 0; d < 64; ++d) rs += Gb[t * 64 + d] / (nc * nrm[d]);
        float dd = 1.0f / sqrtf(rs + 1e-8f);
        if (!(dd <= 3.0e38f)) dd = 0.0f;
        dvv[t] = dd;
    }
    __syncthreads();
    {
        int c = t >> 2;
        int dbase = (t & 3) * 16;
        float nc = nrm[c], dc = dvv[c];
#pragma unroll
        for (int dp2 = 0; dp2 < 8; ++dp2) {
            int d0 = dbase + dp2 * 2;
            float A0 = Gb[c * 64 + d0]     / (nc * nrm[d0]);
            float A1 = Gb[c * 64 + d0 + 1] / (nc * nrm[d0 + 1]);
            float v0 = ((c == d0)     ? 1.f : 0.f) - dc * A0 * dvv[d0];
            float v1 = ((c == d0 + 1) ? 1.f : 0.f) - dc * A1 * dvv[d0 + 1];
            int o = c * 64 + (d0 ^ ((c & 7) << 3));
            *(u32*)&ldsL[o] = (u32)f2bf(v0) | ((u32)f2bf(v1) << 16);
        }
    }
    __syncthreads();

    f32x4 acc[4][2];
#pragma unroll
    for (int mf = 0; mf < 4; ++mf)
#pragma unroll
        for (int nq = 0; nq < 2; ++nq) acc[mf][nq] = (f32x4){0.f, 0.f, 0.f, 0.f};

#pragma unroll
    for (int kk = 0; kk < 2; ++kk) {
        s16x8 bfr[2];
#pragma unroll
        for (int nq = 0; nq < 2; ++nq) {
            int brow = w * 32 + nq * 16 + lr;
            bfr[nq] = *(const s16x8*)((const char*)lds + brow * 128 +
                                      ((kk * 64 + ksub * 16) ^ ((brow & 7) << 4)));
        }
#pragma unroll
        for (int mf = 0; mf < 4; ++mf) {
            int arow = mf * 16 + lr;
            s16x8 af = *(const s16x8*)((const char*)ldsL + arow * 128 +
                                       ((kk * 64 + ksub * 16) ^ ((arow & 7) << 4)));
#pragma unroll
            for (int nq = 0; nq < 2; ++nq)
                acc[mf][nq] = __builtin_amdgcn_mfma_f32_16x16x32_bf16(
                    af, bfr[nq], acc[mf][nq], 0, 0, 0);
        }
    }
#pragma unroll
    for (int mf = 0; mf < 4; ++mf)
#pragma unroll
        for (int nq = 0; nq < 2; ++nq)
#pragma unroll
            for (int r = 0; r < 4; ++r)
                Ab16[((long)(b * 64 + mf * 16 + (l >> 4) * 4 + r)) * 4096 +
                     n0 + w * 32 + nq * 16 + lr] = f2bf(acc[mf][nq][r]);
}

// ---------------------------------------------------------------------------
// K6: bf16 MFMA GEMM, m97-style single-buffer 128x128 tile, KSPLIT=4,
// fragment-native dump (R11/R12-verified fastest gemm config).
#define KSPLIT 4
#define KSLICE 1024
__global__ __launch_bounds__(256) void gemm_mfma_k(const u16* __restrict__ A,
                                                   const u16* __restrict__ WT,
                                                   u16* __restrict__ Cp) {
    __shared__ alignas(16) u16 ldsA[8192];   // 16 KB
    __shared__ alignas(16) u16 ldsB[8192];   // 16 KB
    int bid = blockIdx.x;                    // 512 blocks
    int swz = (bid & 7) * 64 + (bid >> 3);   // XCD-chunked (512 % 8 == 0)
    int m0 = (swz & 3) * 128;
    int n0 = ((swz >> 2) & 31) * 128;
    int z  = swz >> 7;
    int t = threadIdx.x;
    int w = t >> 6, l = t & 63;
    int wr = w >> 1, wc = w & 1;
    int lr = l & 15;
    int lk = (l >> 4) << 4;

    f32x4 acc[4][4];
#pragma unroll
    for (int mf = 0; mf < 4; ++mf)
#pragma unroll
        for (int nf = 0; nf < 4; ++nf) acc[mf][nf] = (f32x4){0.f, 0.f, 0.f, 0.f};

    const char* Ab = (const char*)(A  + (long)m0 * 4096 + z * KSLICE);
    const char* Bb = (const char*)(WT + (long)n0 * 4096 + z * KSLICE);

    for (int k0 = 0; k0 < KSLICE; k0 += 64) {
        __syncthreads();
#pragma unroll
        for (int i = 0; i < 4; ++i) {
            int d   = i * 4096 + t * 16;
            int row = d >> 7;
            int off = d & 127;
            int sk  = off ^ ((row & 7) << 4);
            GLOAD16(Ab + (long)row * 8192 + k0 * 2 + sk, (char*)ldsA + d);
            GLOAD16(Bb + (long)row * 8192 + k0 * 2 + sk, (char*)ldsB + d);
        }
        __syncthreads();
#pragma unroll
        for (int kk = 0; kk < 2; ++kk) {
            s16x8 af[4], bf[4];
#pragma unroll
            for (int f = 0; f < 4; ++f) {
                int ar = wr * 64 + f * 16 + lr;
                af[f] = *(const s16x8*)((const char*)ldsA + ar * 128 +
                                        ((kk * 64 + lk) ^ ((ar & 7) << 4)));
                int br = wc * 64 + f * 16 + lr;
                bf[f] = *(const s16x8*)((const char*)ldsB + br * 128 +
                                        ((kk * 64 + lk) ^ ((br & 7) << 4)));
            }
#pragma unroll
            for (int mf = 0; mf < 4; ++mf)
#pragma unroll
                for (int nf = 0; nf < 4; ++nf)
                    acc[mf][nf] = __builtin_amdgcn_mfma_f32_16x16x32_bf16(
                        af[mf], bf[nf], acc[mf][nf], 0, 0, 0);
        }
    }
    // fragment-native dump: 8 coalesced 16B stores, zero scatter
    int tile = (swz & 3) * 32 + ((swz >> 2) & 31);
    u16 carr[64];
#pragma unroll
    for (int mf = 0; mf < 4; ++mf)
#pragma unroll
        for (int nf = 0; nf < 4; ++nf)
#pragma unroll
            for (int r = 0; r < 4; ++r)
                carr[mf * 16 + nf * 4 + r] = f2bf(acc[mf][nf][r]);
    u16* dp = Cp + ((long)(z * 128 + tile) * 256 + t) * 64;
#pragma unroll
    for (int v8 = 0; v8 < 8; ++v8)
        *(u16x8*)&dp[v8 * 8] = *(const u16x8*)&carr[v8 * 8];
}

// ---------------------------------------------------------------------------
// K6b: reduce 4 z-dumps + transpose -> A2[b*4096+n][c] bf16 (R10-verified).
__global__ __launch_bounds__(256) void reduce4T_k(const u16* __restrict__ Cp,
                                                  u16* __restrict__ A2) {
    __shared__ u16 ldsT[128 * 128];              // [pix][mrow swizzled], 32 KB
    int tile = blockIdx.x;                       // 0..127
    int tm = tile >> 5, tn = tile & 31;
    int n0 = tn * 128;
    int t = threadIdx.x;
    int w = t >> 6, l = t & 63;
    int wr = w >> 1, wc = w & 1, lr = l & 15;

    float s[64];
#pragma unroll
    for (int k = 0; k < 64; ++k) s[k] = 0.f;

    const u16* dp = Cp + ((long)tile * 256 + t) * 64;
#pragma unroll
    for (int z = 0; z < KSPLIT; ++z) {
        const u16* pz = dp + (long)z * 2097152;  // 128*256*64
#pragma unroll
        for (int v8 = 0; v8 < 8; ++v8) {
            u16x8 vv = *(const u16x8*)&pz[v8 * 8];
#pragma unroll
            for (int e = 0; e < 8; ++e) s[v8 * 8 + e] += bf2f(vv[e]);
        }
    }
    // scatter to LDS transposed: ldsT[pix][mrow ^ swz]
#pragma unroll
    for (int mf = 0; mf < 4; ++mf)
#pragma unroll
        for (int nf = 0; nf < 4; ++nf) {
            int mbase = wr * 64 + mf * 16 + (l >> 4) * 4;    // 4-aligned
            int pix   = wc * 64 + nf * 16 + lr;
            int g = (mbase >> 3) ^ (pix & 7);
            int o = pix * 128 + g * 8 + (mbase & 7);
            u32 w0 = (u32)f2bf(s[mf * 16 + nf * 4 + 0]) |
                     ((u32)f2bf(s[mf * 16 + nf * 4 + 1]) << 16);
            u32 w1 = (u32)f2bf(s[mf * 16 + nf * 4 + 2]) |
                     ((u32)f2bf(s[mf * 16 + nf * 4 + 3]) << 16);
            *(u32*)&ldsT[o]     = w0;
            *(u32*)&ldsT[o + 2] = w1;
        }
    __syncthreads();
    int pix_l = t >> 1, bh = t & 1;
    u16* dst = A2 + ((long)((2 * tm + bh) * 4096 + n0 + pix_l)) * 64;
#pragma unroll
    for (int gg = 0; gg < 8; ++gg) {
        int q = bh * 8 + gg;
        u16x8 vv = *(const u16x8*)&ldsT[pix_l * 128 + (q ^ (pix_l & 7)) * 8];
        *(u16x8*)&dst[gg * 8] = vv;
    }
}

// ---------------------------------------------------------------------------
// K7: convT as MFMA GEMM reading clean A2 (R14-verified lean form), 1-D XCD
// grid: the 8 nt-sharers of an A2-tile co-reside on one XCD (L2-hot re-reads).
__global__ __launch_bounds__(256) void convT_mfma_k(const u16* __restrict__ A2,
                                                    const u16* __restrict__ Wb,
                                                    const float* __restrict__ ub,
                                                    const float* __restrict__ x,
                                                    float* __restrict__ out) {
    __shared__ alignas(16) char smem[34816];     // staging 32KB | C-bounce 128x68 f32
    u16*   ldsA = (u16*)smem;
    u16*   ldsB = (u16*)(smem + 16384);
    float* ldsC = (float*)smem;
    int bid = blockIdx.x;                        // 0..2047
    int swzb = (bid & 7) * 256 + (bid >> 3);     // XCD-chunked (2048 % 8 == 0)
    int mt = swzb >> 3;                          // 0..255
    int nt = swzb & 7;                           // 0..7
    int m0 = mt * 128;
    int n0 = nt * 128;
    int t = threadIdx.x;
    int w = t >> 6, l = t & 63;
    int wr = w >> 1, wc = w & 1;
    int lr = l & 15;
    int lkb = (l >> 4) << 4;

    const char* Ab = (const char*)(A2 + (long)m0 * 64);
    const char* Bb = (const char*)(Wb + (long)n0 * 64);
#pragma unroll
    for (int i = 0; i < 4; ++i) {
        int d = i * 4096 + t * 16;
        int srcoff = (d & ~127) | ((d & 127) ^ (((d >> 7) & 7) << 4));
        GLOAD16(Ab + srcoff, (char*)ldsA + d);
        GLOAD16(Bb + srcoff, (char*)ldsB + d);
    }
    __syncthreads();

    f32x4 acc[4][4];
#pragma unroll
    for (int mf = 0; mf < 4; ++mf)
#pragma unroll
        for (int nf = 0; nf < 4; ++nf) acc[mf][nf] = (f32x4){0.f, 0.f, 0.f, 0.f};

#pragma unroll
    for (int kk = 0; kk < 2; ++kk) {
        s16x8 af[4], bfg[4];
#pragma unroll
        for (int f = 0; f < 4; ++f) {
            int ar = wr * 64 + f * 16 + lr;
            af[f] = *(const s16x8*)((const char*)ldsA + ar * 128 +
                                    ((kk * 64 + lkb) ^ ((ar & 7) << 4)));
            int br = wc * 64 + f * 16 + lr;
            bfg[f] = *(const s16x8*)((const char*)ldsB + br * 128 +
                                     ((kk * 64 + lkb) ^ ((br & 7) << 4)));
        }
#pragma unroll
        for (int mf = 0; mf < 4; ++mf)
#pragma unroll
            for (int nf = 0; nf < 4; ++nf)
                acc[mf][nf] = __builtin_amdgcn_mfma_f32_16x16x32_bf16(
                    af[mf], bfg[nf], acc[mf][nf], 0, 0, 0);
    }
    __syncthreads();                             // ldsA/B dead; reuse as ldsC

#pragma unroll
    for (int nh = 0; nh < 2; ++nh) {
        if (nh) __syncthreads();
        if (wc == nh) {
#pragma unroll
            for (int mf = 0; mf < 4; ++mf)
#pragma unroll
                for (int nf = 0; nf < 4; ++nf)
#pragma unroll
                    for (int r = 0; r < 4; ++r) {
                        int row = wr * 64 + mf * 16 + (l >> 4) * 4 + r;
                        int col = nf * 16 + lr;
                        ldsC[row * 68 + (col ^ (((row >> 3) & 7) << 2))] =
                            acc[mf][nf][r];
                    }
        }
        __syncthreads();
#pragma unroll
        for (int q = 0; q < 2; ++q) {
            int idx = q * 256 + t;
            int ml = idx & 127;
            int oo = idx >> 7;
            int o  = nt * 8 + nh * 4 + oo;
            float bias = ub[o];
            int mg = m0 + ml;
            int b = mg >> 12, pix = mg & 4095;
            int h2 = pix >> 6, ww = pix & 63;
            long base = ((long)(b * 64 + o) * 256 + h2 * 4) * 256 + ww * 4;
#pragma unroll
            for (int i = 0; i < 4; ++i) {
                f32x4 cv = *(const f32x4*)&ldsC[ml * 68 +
                            ((oo * 16 + i * 4) ^ (((ml >> 3) & 7) << 2))];
                float4 xi = *(const float4*)&x[base + i * 256];
                float4 rr;
                rr.x = fmaxf(cv[0] + bias + xi.x, 0.f);
                rr.y = fmaxf(cv[1] + bias + xi.y, 0.f);
                rr.z = fmaxf(cv[2] + bias + xi.z, 0.f);
                rr.w = fmaxf(cv[3] + bias + xi.w, 0.f);
                *(float4*)&out[base + i * 256] = rr;
            }
        }
    }
}

// ---------------------------------------------------------------------------
extern "C" void kernel_launch(void* const* d_in, const int* in_sizes, int n_in,
                              void* d_out, int out_size, void* d_ws, size_t ws_size,
                              hipStream_t stream) {
    const float* x      = (const float*)d_in[0];
    const float* weight = (const float*)d_in[1];
    const float* pih_w  = (const float*)d_in[2];
    const float* pih_b  = (const float*)d_in[3];
    const float* up_w   = (const float*)d_in[4];
    const float* up_b   = (const float*)d_in[5];
    float* out = (float*)d_out;
    float* ws  = (float*)d_ws;

    // workspace layout (float offsets)
    u16*   xpc   = (u16*)ws;                   // 2,097,152 u16 NHWC bf16 pooled
    u16*   Ab16  = (u16*)(ws + 3145728);       // 2,097,152 u16 GEMM A bf16
    float* G     = ws + 4194304;               // 32,768 f
    u16*   Wb    = (u16*)(ws + 4259840);       // 65,536 u16 convT B^T bf16
    u16*   WTb   = (u16*)(ws + 4325376);       // 16,777,216 u16 WT bf16 [N][K]
    u16*   Cp    = (u16*)(ws + 12713984);      // 8,388,608 u16: 4 z-partial dumps
    u16*   Bpack = Cp + 2097152;               // conv weights (dead until gemm)
    u16*   A2    = (u16*)ws;                   // out2^T bf16 (xpc dead after diffuse)

    hipMemsetAsync(G, 0, 32768 * sizeof(float), stream);
    front_k       <<<1936, 256, 0, stream>>>(x, weight, up_w, pih_w,
                                             xpc, WTb, Wb, Bpack);
    convgram_k    <<<512, 256, 0, stream>>>(xpc, Bpack, pih_b, G);
    diffuse_mfma_k<<<dim3(32, 8), 256, 0, stream>>>(G, xpc, Ab16);
    gemm_mfma_k   <<<512, 256, 0, stream>>>(Ab16, WTb, Cp);
    reduce4T_k    <<<128, 256, 0, stream>>>(Cp, A2);
    convT_mfma_k  <<<2048, 256, 0, stream>>>(A2, Wb, up_b, x, out);
}